// Round 4
// baseline (279.992 us; speedup 1.0000x reference)
//
#include <hip/hip_runtime.h>
#include <hip/hip_fp16.h>

#define N_NODES 50000
#define N_EDGES 600000
#define NBLK 49  // ceil(50000/1024)

typedef unsigned int u32;
typedef _Float16 v8h __attribute__((ext_vector_type(8)));
typedef _Float16 v4h __attribute__((ext_vector_type(4)));
typedef float v4f __attribute__((ext_vector_type(4)));

__device__ __forceinline__ float2 h2f2(u32 u) {
    __half2 h = *(__half2*)&u;
    return __half22float2(h);
}

// ---------------- adj layout detection (int64 vs int32), computed per-wave ----------------
__device__ __forceinline__ int calc_mode(const int* __restrict__ adj_w) {
    int l = threadIdx.x & 63;
    unsigned long long b = __ballot(adj_w[2 * l + 1] != 0);
    return (b == 0ull) ? 1 : 0;
}
// vectorized edge load: int64 mode = one uint4 (fro=lo(x), to=lo(z)); int32 = uint2
__device__ __forceinline__ void load_edge(const int* __restrict__ a, int m, int e,
                                          int& fro, int& to) {
    if (m) {
        uint4 v = ((const uint4*)a)[e];
        fro = (int)v.x;
        to = (int)v.z;
    } else {
        uint2 v = ((const uint2*)a)[e];
        fro = (int)v.x;
        to = (int)v.y;
    }
}

#define CNT_B   293    // ceil(600000/(256*8)); 8 edges per thread
#define WPREP_B 344    // ceil(88064/256)
#define IN_B    1563   // ceil(50000/32)

// ---- merged: edge count (atomic, keeps rank) + weight transpose/convert ----
__global__ void k_count_prep(const int* __restrict__ adj_w, int* __restrict__ deg,
                             int* __restrict__ rank,
                             const float* __restrict__ W_in,
                             const float* __restrict__ W_comb,
                             const float* __restrict__ W_out,
                             _Float16* __restrict__ WinT,
                             _Float16* __restrict__ WcombT,
                             _Float16* __restrict__ WoutT) {
    if (blockIdx.x < CNT_B) {
        int m = calc_mode(adj_w);
        int base = blockIdx.x * 2048 + threadIdx.x;
        int to[8], r[8];
#pragma unroll
        for (int i = 0; i < 8; i++) {
            int e = base + i * 256;
            if (e < N_EDGES) {
                int f;
                load_edge(adj_w, m, e, f, to[i]);
            } else {
                to[i] = -1;
            }
        }
#pragma unroll
        for (int i = 0; i < 8; i++)
            if (to[i] >= 0) r[i] = atomicAdd(&deg[to[i]], 1);
#pragma unroll
        for (int i = 0; i < 8; i++) {
            int e = base + i * 256;
            if (e < N_EDGES) rank[e] = r[i];
        }
        return;
    }
    int idx = (blockIdx.x - CNT_B) * 256 + threadIdx.x;
    if (idx < 16384) {
        int n = idx & 127, k = idx >> 7;
        WinT[n * 128 + k] = (_Float16)W_in[k * 128 + n];
    } else if (idx < 16384 + 65536) {
        int j = idx - 16384;
        int l = j >> 15, r = j & 32767;
        int n = r & 127, k = r >> 7;
        WcombT[l * 32768 + n * 256 + k] = (_Float16)W_comb[l * 32768 + k * 128 + n];
    } else if (idx < 16384 + 65536 + 6144) {
        int j = idx - 81920;
        int n = j >> 7, k = j & 127;
        WoutT[n * 128 + k] = (n < 40) ? (_Float16)W_out[k * 40 + n] : (_Float16)0.f;
    }
}

// ---- single-kernel CSR scan: per-block LDS scan + 49-block lookback ----
__global__ void k_scan(const int* __restrict__ deg, int* __restrict__ row_ptr,
                       float* __restrict__ inv_deg, int* __restrict__ bsync) {
    __shared__ int s[1024];
    __shared__ int sbase;
    const int tid = threadIdx.x, b = blockIdx.x;
    const int i = b * 1024 + tid;
    int v = (i < N_NODES) ? deg[i] : 0;
    s[tid] = v;
    __syncthreads();
    for (int off = 1; off < 1024; off <<= 1) {
        int t = (tid >= off) ? s[tid - off] : 0;
        __syncthreads();
        s[tid] += t;
        __syncthreads();
    }
    if (tid == 1023)
        __hip_atomic_store(&bsync[b], 0x40000000 | s[1023], __ATOMIC_RELEASE,
                           __HIP_MEMORY_SCOPE_AGENT);
    if (tid < 64) {
        int acc = 0;
        if (tid < b) {
            int x;
            do {
                x = __hip_atomic_load(&bsync[tid], __ATOMIC_ACQUIRE,
                                      __HIP_MEMORY_SCOPE_AGENT);
            } while (x < 0x40000000);
            acc = x & 0x3fffffff;
        }
#pragma unroll
        for (int off = 32; off > 0; off >>= 1) acc += __shfl_down(acc, off);
        if (tid == 0) sbase = acc;
    }
    __syncthreads();
    if (i < N_NODES) {
        row_ptr[i] = sbase + s[tid] - v;  // exclusive prefix
        inv_deg[i] = 1.0f / fmaxf((float)v, 1.0f);
    }
    if (i == 0) row_ptr[N_NODES] = N_EDGES;
}

// ---- merged: atomic-free CSR fill (rank trick) + input GEMM ----
__global__ __launch_bounds__(256, 2) void k_fill_in(const int* __restrict__ adj_w,
                                                    const int* __restrict__ row_ptr,
                                                    const int* __restrict__ rank,
                                                    int* __restrict__ edge_src,
                                                    const float* __restrict__ X,
                                                    const _Float16* __restrict__ WT,
                                                    const float* __restrict__ bias,
                                                    _Float16* __restrict__ h) {
    __shared__ __align__(16) _Float16 xs[32][136];
    if (blockIdx.x < CNT_B) {
        int m = calc_mode(adj_w);
        int base = blockIdx.x * 2048 + threadIdx.x;
        int to[8], fro[8], rk[8];
#pragma unroll
        for (int i = 0; i < 8; i++) {
            int e = base + i * 256;
            if (e < N_EDGES) {
                load_edge(adj_w, m, e, fro[i], to[i]);
                rk[i] = rank[e];
            } else {
                to[i] = -1;
            }
        }
#pragma unroll
        for (int i = 0; i < 8; i++)
            if (to[i] >= 0) edge_src[row_ptr[to[i]] + rk[i]] = fro[i];
        return;
    }
    const int t0 = threadIdx.x, w = t0 >> 6, l = t0 & 63;
    const int R0 = (blockIdx.x - CNT_B) * 32;
    const float4* X4 = (const float4*)X;
#pragma unroll
    for (int i = 0; i < 4; i++) {
        int idx = i * 256 + t0;
        int row = idx >> 5, c4 = idx & 31;
        int rr = R0 + row;
        if (rr > N_NODES - 1) rr = N_NODES - 1;
        float4 v = X4[(size_t)rr * 32 + c4];
        v4h hv = {(_Float16)v.x, (_Float16)v.y, (_Float16)v.z, (_Float16)v.w};
        *(v4h*)&xs[row][c4 * 4] = hv;
    }
    const int ch = w & 1, rh = w >> 1;
    v8h wf[4][4];
#pragma unroll
    for (int t = 0; t < 4; t++)
#pragma unroll
        for (int s = 0; s < 4; s++) {
            int n = ch * 64 + t * 16 + (l & 15);
            int k = s * 32 + (l >> 4) * 8;
            wf[t][s] = *(const v8h*)&WT[n * 128 + k];
        }
    v4f acc[4];
#pragma unroll
    for (int t = 0; t < 4; t++) acc[t] = (v4f){0.f, 0.f, 0.f, 0.f};
    __syncthreads();
#pragma unroll
    for (int s = 0; s < 4; s++) {
        v8h a = *(const v8h*)&xs[rh * 16 + (l & 15)][s * 32 + (l >> 4) * 8];
#pragma unroll
        for (int t = 0; t < 4; t++)
            acc[t] = __builtin_amdgcn_mfma_f32_16x16x32_f16(a, wf[t][s], acc[t], 0, 0, 0);
    }
#pragma unroll
    for (int t = 0; t < 4; t++) {
        int col = ch * 64 + t * 16 + (l & 15);
        float b = bias[col];
#pragma unroll
        for (int i = 0; i < 4; i++) {
            int row = R0 + rh * 16 + (l >> 4) * 4 + i;
            if (row < N_NODES)
                h[(size_t)row * 128 + col] = (_Float16)fmaxf(acc[t][i] + b, 0.f);
        }
    }
}

// ---- in-block gather: each 16-lane group owns one dest row; 4 edges in flight;
// writes straight into the xs msg-half. No shuffles, no msg buffer. ----
__device__ __forceinline__ void gather_tile(_Float16 (*xs)[264], const int* rp,
                                            const float* sinv, const uint4* __restrict__ hh,
                                            const int* __restrict__ edge_src,
                                            int w, int l) {
    const int g = l >> 4, c = l & 15;
#pragma unroll
    for (int j = 0; j < 4; j++) {
        int lrow = w * 16 + g * 4 + j;
        int e0 = rp[lrow], e1 = rp[lrow + 1];
        float a[8];
#pragma unroll
        for (int k = 0; k < 8; k++) a[k] = 0.f;
        for (int bse = e0; bse < e1; bse += 4) {
            uint4 v[4];
            int ok[4];
#pragma unroll
            for (int i = 0; i < 4; i++) {
                int ee = bse + i;
                ok[i] = (ee < e1);
                int idx = ok[i] ? ee : (e1 - 1);
                v[i] = hh[(size_t)edge_src[idx] * 16 + c];
            }
#pragma unroll
            for (int i = 0; i < 4; i++) {
                if (ok[i]) {
                    u32 u[4] = {v[i].x, v[i].y, v[i].z, v[i].w};
#pragma unroll
                    for (int k = 0; k < 4; k++) {
                        float2 f = h2f2(u[k]);
                        a[2 * k] += f.x;
                        a[2 * k + 1] += f.y;
                    }
                }
            }
        }
        const float inv = sinv[lrow];
        __half2 o0 = __floats2half2_rn(a[0] * inv, a[1] * inv);
        __half2 o1 = __floats2half2_rn(a[2] * inv, a[3] * inv);
        __half2 o2 = __floats2half2_rn(a[4] * inv, a[5] * inv);
        __half2 o3 = __floats2half2_rn(a[6] * inv, a[7] * inv);
        uint4 o;
        o.x = *(u32*)&o0;
        o.y = *(u32*)&o1;
        o.z = *(u32*)&o2;
        o.w = *(u32*)&o3;
        *(uint4*)&xs[lrow][128 + c * 8] = o;
    }
}

// ---- fused gather + layer GEMM ----
__global__ __launch_bounds__(256, 2) void k_layer(const _Float16* __restrict__ hin,
                                                  const _Float16* __restrict__ WT,
                                                  const float* __restrict__ bias,
                                                  const int* __restrict__ row_ptr,
                                                  const int* __restrict__ edge_src,
                                                  const float* __restrict__ inv_deg,
                                                  _Float16* __restrict__ hout) {
    __shared__ __align__(16) _Float16 xs[64][264];  // 33.8KB
    __shared__ int rp[65];
    __shared__ float sinv[64];
    const int t0 = threadIdx.x, w = t0 >> 6, l = t0 & 63;
    const int R0 = blockIdx.x * 64;
    if (t0 < 65) {
        int rr = R0 + t0;
        if (rr > N_NODES) rr = N_NODES;
        rp[t0] = row_ptr[rr];
    } else if (t0 >= 128 && t0 < 192) {
        int rr = R0 + (t0 - 128);
        if (rr > N_NODES - 1) rr = N_NODES - 1;
        sinv[t0 - 128] = inv_deg[rr];
    }
    const uint4* h4 = (const uint4*)hin;
#pragma unroll
    for (int i = 0; i < 4; i++) {
        int idx = i * 256 + t0;
        int row = idx >> 4, c16 = idx & 15;
        int rr = R0 + row;
        if (rr > N_NODES - 1) rr = N_NODES - 1;
        *(uint4*)&xs[row][c16 * 8] = h4[(size_t)rr * 16 + c16];
    }
    __syncthreads();  // rp/sinv ready
    gather_tile(xs, rp, sinv, h4, edge_src, w, l);
    const int ch = w & 1, rh = w >> 1;
    v8h wf[4][8];
#pragma unroll
    for (int t = 0; t < 4; t++)
#pragma unroll
        for (int s = 0; s < 8; s++) {
            int n = ch * 64 + t * 16 + (l & 15);
            int k = s * 32 + (l >> 4) * 8;
            wf[t][s] = *(const v8h*)&WT[n * 256 + k];
        }
    v4f acc[2][4];
#pragma unroll
    for (int sub = 0; sub < 2; sub++)
#pragma unroll
        for (int t = 0; t < 4; t++) acc[sub][t] = (v4f){0.f, 0.f, 0.f, 0.f};
    __syncthreads();
#pragma unroll
    for (int s = 0; s < 8; s++) {
#pragma unroll
        for (int sub = 0; sub < 2; sub++) {
            v8h a = *(const v8h*)&xs[rh * 32 + sub * 16 + (l & 15)][s * 32 + (l >> 4) * 8];
#pragma unroll
            for (int t = 0; t < 4; t++)
                acc[sub][t] = __builtin_amdgcn_mfma_f32_16x16x32_f16(a, wf[t][s], acc[sub][t], 0, 0, 0);
        }
    }
#pragma unroll
    for (int sub = 0; sub < 2; sub++)
#pragma unroll
        for (int t = 0; t < 4; t++) {
            int col = ch * 64 + t * 16 + (l & 15);
            float b = bias[col];
#pragma unroll
            for (int i = 0; i < 4; i++) {
                int row = R0 + rh * 32 + sub * 16 + (l >> 4) * 4 + i;
                if (row < N_NODES)
                    hout[(size_t)row * 128 + col] = (_Float16)fmaxf(acc[sub][t][i] + b, 0.f);
            }
        }
}

// ---- fused gather + layer-2 + out-GEMM ----
__global__ __launch_bounds__(256, 2) void k_layer_out(const _Float16* __restrict__ hin,
                                                      const _Float16* __restrict__ WT,
                                                      const float* __restrict__ bias,
                                                      const int* __restrict__ row_ptr,
                                                      const int* __restrict__ edge_src,
                                                      const float* __restrict__ inv_deg,
                                                      const _Float16* __restrict__ WoT,
                                                      const float* __restrict__ bias_o,
                                                      float* __restrict__ outp) {
    __shared__ __align__(16) _Float16 xs[64][264];
    __shared__ int rp[65];
    __shared__ float sinv[64];
    const int t0 = threadIdx.x, w = t0 >> 6, l = t0 & 63;
    const int R0 = blockIdx.x * 64;
    if (t0 < 65) {
        int rr = R0 + t0;
        if (rr > N_NODES) rr = N_NODES;
        rp[t0] = row_ptr[rr];
    } else if (t0 >= 128 && t0 < 192) {
        int rr = R0 + (t0 - 128);
        if (rr > N_NODES - 1) rr = N_NODES - 1;
        sinv[t0 - 128] = inv_deg[rr];
    }
    const uint4* h4 = (const uint4*)hin;
#pragma unroll
    for (int i = 0; i < 4; i++) {
        int idx = i * 256 + t0;
        int row = idx >> 4, c16 = idx & 15;
        int rr = R0 + row;
        if (rr > N_NODES - 1) rr = N_NODES - 1;
        *(uint4*)&xs[row][c16 * 8] = h4[(size_t)rr * 16 + c16];
    }
    __syncthreads();
    gather_tile(xs, rp, sinv, h4, edge_src, w, l);
    const int ch = w & 1, rh = w >> 1;
    v8h wf[4][8];
#pragma unroll
    for (int t = 0; t < 4; t++)
#pragma unroll
        for (int s = 0; s < 8; s++) {
            int n = ch * 64 + t * 16 + (l & 15);
            int k = s * 32 + (l >> 4) * 8;
            wf[t][s] = *(const v8h*)&WT[n * 256 + k];
        }
    v4f acc[2][4];
#pragma unroll
    for (int sub = 0; sub < 2; sub++)
#pragma unroll
        for (int t = 0; t < 4; t++) acc[sub][t] = (v4f){0.f, 0.f, 0.f, 0.f};
    __syncthreads();
#pragma unroll
    for (int s = 0; s < 8; s++) {
#pragma unroll
        for (int sub = 0; sub < 2; sub++) {
            v8h a = *(const v8h*)&xs[rh * 32 + sub * 16 + (l & 15)][s * 32 + (l >> 4) * 8];
#pragma unroll
            for (int t = 0; t < 4; t++)
                acc[sub][t] = __builtin_amdgcn_mfma_f32_16x16x32_f16(a, wf[t][s], acc[sub][t], 0, 0, 0);
        }
    }
    __syncthreads();  // all xs reads done; safe to overwrite with h2 tile
    _Float16* hs = &xs[0][0];  // reused as [64][136]
#pragma unroll
    for (int sub = 0; sub < 2; sub++)
#pragma unroll
        for (int t = 0; t < 4; t++) {
            int col = ch * 64 + t * 16 + (l & 15);
            float b = bias[col];
#pragma unroll
            for (int i = 0; i < 4; i++) {
                int lrow = rh * 32 + sub * 16 + (l >> 4) * 4 + i;
                hs[lrow * 136 + col] = (_Float16)fmaxf(acc[sub][t][i] + b, 0.f);
            }
        }
    v8h wo[3][4];
#pragma unroll
    for (int t = 0; t < 3; t++)
#pragma unroll
        for (int s = 0; s < 4; s++) {
            int n = t * 16 + (l & 15);
            int k = s * 32 + (l >> 4) * 8;
            wo[t][s] = *(const v8h*)&WoT[n * 128 + k];
        }
    v4f acc2[3];
#pragma unroll
    for (int t = 0; t < 3; t++) acc2[t] = (v4f){0.f, 0.f, 0.f, 0.f};
    __syncthreads();
#pragma unroll
    for (int s = 0; s < 4; s++) {
        v8h a = *(const v8h*)&hs[(w * 16 + (l & 15)) * 136 + s * 32 + (l >> 4) * 8];
#pragma unroll
        for (int t = 0; t < 3; t++)
            acc2[t] = __builtin_amdgcn_mfma_f32_16x16x32_f16(a, wo[t][s], acc2[t], 0, 0, 0);
    }
#pragma unroll
    for (int t = 0; t < 3; t++) {
        int col = t * 16 + (l & 15);
        if (col < 40) {
            float b = bias_o[col];
#pragma unroll
            for (int i = 0; i < 4; i++) {
                int row = R0 + w * 16 + (l >> 4) * 4 + i;
                if (row < N_NODES) outp[(size_t)row * 40 + col] = acc2[t][i] + b;
            }
        }
    }
}

extern "C" void kernel_launch(void* const* d_in, const int* in_sizes, int n_in,
                              void* d_out, int out_size, void* d_ws, size_t ws_size,
                              hipStream_t stream) {
    int ix[8] = {0, 1, 2, 3, 4, 5, 6, 7};
    int tmp[8] = {-1, -1, -1, -1, -1, -1, -1, -1};
    for (int i = 0; i < n_in && i < 8; i++) {
        switch (in_sizes[i]) {
            case 6400000: tmp[0] = i; break;
            case 1200000: case 2400000: tmp[1] = i; break;
            case 16384:   tmp[2] = i; break;
            case 128:     tmp[3] = i; break;
            case 65536:   tmp[4] = i; break;
            case 256:     tmp[5] = i; break;
            case 5120:    tmp[6] = i; break;
            case 40:      tmp[7] = i; break;
        }
    }
    int found = 0;
    for (int j = 0; j < 8; j++) found += (tmp[j] >= 0);
    if (found == 8) for (int j = 0; j < 8; j++) ix[j] = tmp[j];

    const float* X      = (const float*)d_in[ix[0]];
    const int*   adj_w  = (const int*)d_in[ix[1]];
    const float* W_in   = (const float*)d_in[ix[2]];
    const float* b_in   = (const float*)d_in[ix[3]];
    const float* W_comb = (const float*)d_in[ix[4]];
    const float* b_comb = (const float*)d_in[ix[5]];
    const float* W_out  = (const float*)d_in[ix[6]];
    const float* b_out  = (const float*)d_in[ix[7]];
    float* out = (float*)d_out;

    // ws layout (bytes)
    char* base = (char*)d_ws;
    int*      deg      = (int*)(base + 0);           // 200000
    int*      bsync    = (int*)(base + 200000);      // 256 (zeroed with deg)
    int*      row_ptr  = (int*)(base + 200256);      // 200004
    int*      rank     = (int*)(base + 400272);      // 2400000
    float*    inv_deg  = (float*)(base + 2800272);   // 200000
    int*      edge_src = (int*)(base + 3000272);     // 2400000
    _Float16* WinT     = (_Float16*)(base + 5400272);
    _Float16* WcombT   = (_Float16*)(base + 5433040);
    _Float16* WoutT    = (_Float16*)(base + 5564112);
    _Float16* hA       = (_Float16*)(base + 5576448);
    _Float16* hB       = (_Float16*)(base + 18376448);

    hipMemsetAsync(deg, 0, 200256, stream);  // deg + bsync
    k_count_prep<<<CNT_B + WPREP_B, 256, 0, stream>>>(adj_w, deg, rank, W_in, W_comb, W_out,
                                                      WinT, WcombT, WoutT);
    k_scan<<<NBLK, 1024, 0, stream>>>(deg, row_ptr, inv_deg, bsync);
    k_fill_in<<<CNT_B + IN_B, 256, 0, stream>>>(adj_w, row_ptr, rank, edge_src,
                                                X, WinT, b_in, hA);

    k_layer<<<782, 256, 0, stream>>>(hA, WcombT, b_comb, row_ptr, edge_src, inv_deg, hB);
    k_layer_out<<<782, 256, 0, stream>>>(hB, WcombT + 32768, b_comb + 128,
                                         row_ptr, edge_src, inv_deg, WoutT, b_out, out);
}

// Round 5
// 273.513 us; speedup vs baseline: 1.0237x; 1.0237x over previous
//
#include <hip/hip_runtime.h>
#include <hip/hip_fp16.h>

#define N_NODES 50000
#define N_EDGES 600000
#define NBLK 49  // ceil(50000/1024)

typedef unsigned int u32;
typedef _Float16 v8h __attribute__((ext_vector_type(8)));
typedef _Float16 v4h __attribute__((ext_vector_type(4)));
typedef float v4f __attribute__((ext_vector_type(4)));

__device__ __forceinline__ float2 h2f2(u32 u) {
    __half2 h = *(__half2*)&u;
    return __half22float2(h);
}

// ---------------- adj layout detection (int64 vs int32), computed per-wave ----------------
__device__ __forceinline__ int calc_mode(const int* __restrict__ adj_w) {
    int l = threadIdx.x & 63;
    unsigned long long b = __ballot(adj_w[2 * l + 1] != 0);
    return (b == 0ull) ? 1 : 0;
}
// vectorized edge load: int64 mode = one uint4 (fro=lo(x), to=lo(z)); int32 = uint2
__device__ __forceinline__ void load_edge(const int* __restrict__ a, int m, int e,
                                          int& fro, int& to) {
    if (m) {
        uint4 v = ((const uint4*)a)[e];
        fro = (int)v.x;
        to = (int)v.z;
    } else {
        uint2 v = ((const uint2*)a)[e];
        fro = (int)v.x;
        to = (int)v.y;
    }
}

#define CNT_B   293    // ceil(600000/(256*8)); 8 edges per thread
#define WPREP_B 344    // ceil(88064/256)
#define IN_B    1563   // ceil(50000/32)
#define LYR_B   1563   // ceil(50000/32)

// ---- merged: edge count (atomic, keeps rank) + weight transpose/convert ----
__global__ void k_count_prep(const int* __restrict__ adj_w, int* __restrict__ deg,
                             int* __restrict__ rank,
                             const float* __restrict__ W_in,
                             const float* __restrict__ W_comb,
                             const float* __restrict__ W_out,
                             _Float16* __restrict__ WinT,
                             _Float16* __restrict__ WcombT,
                             _Float16* __restrict__ WoutT) {
    if (blockIdx.x < CNT_B) {
        int m = calc_mode(adj_w);
        int base = blockIdx.x * 2048 + threadIdx.x;
        int to[8], r[8];
#pragma unroll
        for (int i = 0; i < 8; i++) {
            int e = base + i * 256;
            if (e < N_EDGES) {
                int f;
                load_edge(adj_w, m, e, f, to[i]);
            } else {
                to[i] = -1;
            }
        }
#pragma unroll
        for (int i = 0; i < 8; i++)
            if (to[i] >= 0) r[i] = atomicAdd(&deg[to[i]], 1);
#pragma unroll
        for (int i = 0; i < 8; i++) {
            int e = base + i * 256;
            if (e < N_EDGES) rank[e] = r[i];
        }
        return;
    }
    int idx = (blockIdx.x - CNT_B) * 256 + threadIdx.x;
    if (idx < 16384) {
        int n = idx & 127, k = idx >> 7;
        WinT[n * 128 + k] = (_Float16)W_in[k * 128 + n];
    } else if (idx < 16384 + 65536) {
        int j = idx - 16384;
        int l = j >> 15, r = j & 32767;
        int n = r & 127, k = r >> 7;
        WcombT[l * 32768 + n * 256 + k] = (_Float16)W_comb[l * 32768 + k * 128 + n];
    } else if (idx < 16384 + 65536 + 6144) {
        int j = idx - 81920;
        int n = j >> 7, k = j & 127;
        WoutT[n * 128 + k] = (n < 40) ? (_Float16)W_out[k * 40 + n] : (_Float16)0.f;
    }
}

// ---- single-kernel CSR scan: per-block LDS scan + 49-block lookback ----
__global__ void k_scan(const int* __restrict__ deg, int* __restrict__ row_ptr,
                       float* __restrict__ inv_deg, int* __restrict__ bsync) {
    __shared__ int s[1024];
    __shared__ int sbase;
    const int tid = threadIdx.x, b = blockIdx.x;
    const int i = b * 1024 + tid;
    int v = (i < N_NODES) ? deg[i] : 0;
    s[tid] = v;
    __syncthreads();
    for (int off = 1; off < 1024; off <<= 1) {
        int t = (tid >= off) ? s[tid - off] : 0;
        __syncthreads();
        s[tid] += t;
        __syncthreads();
    }
    if (tid == 1023)
        __hip_atomic_store(&bsync[b], 0x40000000 | s[1023], __ATOMIC_RELEASE,
                           __HIP_MEMORY_SCOPE_AGENT);
    if (tid < 64) {
        int acc = 0;
        if (tid < b) {
            int x;
            do {
                x = __hip_atomic_load(&bsync[tid], __ATOMIC_ACQUIRE,
                                      __HIP_MEMORY_SCOPE_AGENT);
            } while (x < 0x40000000);
            acc = x & 0x3fffffff;
        }
#pragma unroll
        for (int off = 32; off > 0; off >>= 1) acc += __shfl_down(acc, off);
        if (tid == 0) sbase = acc;
    }
    __syncthreads();
    if (i < N_NODES) {
        row_ptr[i] = sbase + s[tid] - v;  // exclusive prefix
        inv_deg[i] = 1.0f / fmaxf((float)v, 1.0f);
    }
    if (i == 0) row_ptr[N_NODES] = N_EDGES;
}

// ---- merged: atomic-free CSR fill (rank trick) + input GEMM ----
__global__ __launch_bounds__(256, 2) void k_fill_in(const int* __restrict__ adj_w,
                                                    const int* __restrict__ row_ptr,
                                                    const int* __restrict__ rank,
                                                    int* __restrict__ edge_src,
                                                    const float* __restrict__ X,
                                                    const _Float16* __restrict__ WT,
                                                    const float* __restrict__ bias,
                                                    _Float16* __restrict__ h) {
    __shared__ __align__(16) _Float16 xs[32][136];
    if (blockIdx.x < CNT_B) {
        int m = calc_mode(adj_w);
        int base = blockIdx.x * 2048 + threadIdx.x;
        int to[8], fro[8], rk[8];
#pragma unroll
        for (int i = 0; i < 8; i++) {
            int e = base + i * 256;
            if (e < N_EDGES) {
                load_edge(adj_w, m, e, fro[i], to[i]);
                rk[i] = rank[e];
            } else {
                to[i] = -1;
            }
        }
#pragma unroll
        for (int i = 0; i < 8; i++)
            if (to[i] >= 0) edge_src[row_ptr[to[i]] + rk[i]] = fro[i];
        return;
    }
    const int t0 = threadIdx.x, w = t0 >> 6, l = t0 & 63;
    const int R0 = (blockIdx.x - CNT_B) * 32;
    const float4* X4 = (const float4*)X;
#pragma unroll
    for (int i = 0; i < 4; i++) {
        int idx = i * 256 + t0;
        int row = idx >> 5, c4 = idx & 31;
        int rr = R0 + row;
        if (rr > N_NODES - 1) rr = N_NODES - 1;
        float4 v = X4[(size_t)rr * 32 + c4];
        v4h hv = {(_Float16)v.x, (_Float16)v.y, (_Float16)v.z, (_Float16)v.w};
        *(v4h*)&xs[row][c4 * 4] = hv;
    }
    const int ch = w & 1, rh = w >> 1;
    v8h wf[4][4];
#pragma unroll
    for (int t = 0; t < 4; t++)
#pragma unroll
        for (int s = 0; s < 4; s++) {
            int n = ch * 64 + t * 16 + (l & 15);
            int k = s * 32 + (l >> 4) * 8;
            wf[t][s] = *(const v8h*)&WT[n * 128 + k];
        }
    v4f acc[4];
#pragma unroll
    for (int t = 0; t < 4; t++) acc[t] = (v4f){0.f, 0.f, 0.f, 0.f};
    __syncthreads();
#pragma unroll
    for (int s = 0; s < 4; s++) {
        v8h a = *(const v8h*)&xs[rh * 16 + (l & 15)][s * 32 + (l >> 4) * 8];
#pragma unroll
        for (int t = 0; t < 4; t++)
            acc[t] = __builtin_amdgcn_mfma_f32_16x16x32_f16(a, wf[t][s], acc[t], 0, 0, 0);
    }
#pragma unroll
    for (int t = 0; t < 4; t++) {
        int col = ch * 64 + t * 16 + (l & 15);
        float b = bias[col];
#pragma unroll
        for (int i = 0; i < 4; i++) {
            int row = R0 + rh * 16 + (l >> 4) * 4 + i;
            if (row < N_NODES)
                h[(size_t)row * 128 + col] = (_Float16)fmaxf(acc[t][i] + b, 0.f);
        }
    }
}

// ---- in-block gather (M=32 tile): each 16-lane group owns 2 dest rows;
// 4 edges in flight; writes straight into the xs msg-half. ----
__device__ __forceinline__ void gather_tile32(_Float16 (*xs)[264], const int* rp,
                                              const float* sinv,
                                              const uint4* __restrict__ hh,
                                              const int* __restrict__ edge_src,
                                              int t0) {
    const int g = t0 >> 4, c = t0 & 15;  // g: 0..15, 16-lane group; c: 16B chunk
#pragma unroll
    for (int j = 0; j < 2; j++) {
        int lrow = g * 2 + j;
        int e0 = rp[lrow], e1 = rp[lrow + 1];
        float a[8];
#pragma unroll
        for (int k = 0; k < 8; k++) a[k] = 0.f;
        for (int bse = e0; bse < e1; bse += 4) {
            uint4 v[4];
            int ok[4];
#pragma unroll
            for (int i = 0; i < 4; i++) {
                int ee = bse + i;
                ok[i] = (ee < e1);
                int idx = ok[i] ? ee : (e1 - 1);
                v[i] = hh[(size_t)edge_src[idx] * 16 + c];
            }
#pragma unroll
            for (int i = 0; i < 4; i++) {
                if (ok[i]) {
                    u32 u[4] = {v[i].x, v[i].y, v[i].z, v[i].w};
#pragma unroll
                    for (int k = 0; k < 4; k++) {
                        float2 f = h2f2(u[k]);
                        a[2 * k] += f.x;
                        a[2 * k + 1] += f.y;
                    }
                }
            }
        }
        const float inv = sinv[lrow];
        __half2 o0 = __floats2half2_rn(a[0] * inv, a[1] * inv);
        __half2 o1 = __floats2half2_rn(a[2] * inv, a[3] * inv);
        __half2 o2 = __floats2half2_rn(a[4] * inv, a[5] * inv);
        __half2 o3 = __floats2half2_rn(a[6] * inv, a[7] * inv);
        uint4 o;
        o.x = *(u32*)&o0;
        o.y = *(u32*)&o1;
        o.z = *(u32*)&o2;
        o.w = *(u32*)&o3;
        *(uint4*)&xs[lrow][128 + c * 8] = o;
    }
}

// ---- fused gather + layer GEMM, M-tile 32, K=256, N=128; ~17KB LDS, 4 blk/CU ----
__global__ __launch_bounds__(256, 4) void k_layer(const _Float16* __restrict__ hin,
                                                  const _Float16* __restrict__ WT,
                                                  const float* __restrict__ bias,
                                                  const int* __restrict__ row_ptr,
                                                  const int* __restrict__ edge_src,
                                                  const float* __restrict__ inv_deg,
                                                  _Float16* __restrict__ hout) {
    __shared__ __align__(16) _Float16 xs[32][264];  // 16.9KB
    __shared__ int rp[33];
    __shared__ float sinv[32];
    const int t0 = threadIdx.x, w = t0 >> 6, l = t0 & 63;
    const int R0 = blockIdx.x * 32;
    if (t0 < 33) {
        int rr = R0 + t0;
        if (rr > N_NODES) rr = N_NODES;
        rp[t0] = row_ptr[rr];
    } else if (t0 >= 64 && t0 < 96) {
        int rr = R0 + (t0 - 64);
        if (rr > N_NODES - 1) rr = N_NODES - 1;
        sinv[t0 - 64] = inv_deg[rr];
    }
    const uint4* h4 = (const uint4*)hin;
#pragma unroll
    for (int i = 0; i < 2; i++) {
        int idx = i * 256 + t0;
        int row = idx >> 4, c16 = idx & 15;
        int rr = R0 + row;
        if (rr > N_NODES - 1) rr = N_NODES - 1;
        *(uint4*)&xs[row][c16 * 8] = h4[(size_t)rr * 16 + c16];
    }
    __syncthreads();  // rp/sinv ready
    gather_tile32(xs, rp, sinv, h4, edge_src, t0);
    const int ch = w & 1, rh = w >> 1;
    v8h wf[4][8];
#pragma unroll
    for (int t = 0; t < 4; t++)
#pragma unroll
        for (int s = 0; s < 8; s++) {
            int n = ch * 64 + t * 16 + (l & 15);
            int k = s * 32 + (l >> 4) * 8;
            wf[t][s] = *(const v8h*)&WT[n * 256 + k];
        }
    v4f acc[4];
#pragma unroll
    for (int t = 0; t < 4; t++) acc[t] = (v4f){0.f, 0.f, 0.f, 0.f};
    __syncthreads();
#pragma unroll
    for (int s = 0; s < 8; s++) {
        v8h a = *(const v8h*)&xs[rh * 16 + (l & 15)][s * 32 + (l >> 4) * 8];
#pragma unroll
        for (int t = 0; t < 4; t++)
            acc[t] = __builtin_amdgcn_mfma_f32_16x16x32_f16(a, wf[t][s], acc[t], 0, 0, 0);
    }
#pragma unroll
    for (int t = 0; t < 4; t++) {
        int col = ch * 64 + t * 16 + (l & 15);
        float b = bias[col];
#pragma unroll
        for (int i = 0; i < 4; i++) {
            int row = R0 + rh * 16 + (l >> 4) * 4 + i;
            if (row < N_NODES)
                hout[(size_t)row * 128 + col] = (_Float16)fmaxf(acc[t][i] + b, 0.f);
        }
    }
}

// ---- fused gather + layer-2 + out-GEMM, M-tile 32 ----
__global__ __launch_bounds__(256, 4) void k_layer_out(const _Float16* __restrict__ hin,
                                                      const _Float16* __restrict__ WT,
                                                      const float* __restrict__ bias,
                                                      const int* __restrict__ row_ptr,
                                                      const int* __restrict__ edge_src,
                                                      const float* __restrict__ inv_deg,
                                                      const _Float16* __restrict__ WoT,
                                                      const float* __restrict__ bias_o,
                                                      float* __restrict__ outp) {
    __shared__ __align__(16) _Float16 xs[32][264];
    __shared__ int rp[33];
    __shared__ float sinv[32];
    const int t0 = threadIdx.x, w = t0 >> 6, l = t0 & 63;
    const int R0 = blockIdx.x * 32;
    if (t0 < 33) {
        int rr = R0 + t0;
        if (rr > N_NODES) rr = N_NODES;
        rp[t0] = row_ptr[rr];
    } else if (t0 >= 64 && t0 < 96) {
        int rr = R0 + (t0 - 64);
        if (rr > N_NODES - 1) rr = N_NODES - 1;
        sinv[t0 - 64] = inv_deg[rr];
    }
    const uint4* h4 = (const uint4*)hin;
#pragma unroll
    for (int i = 0; i < 2; i++) {
        int idx = i * 256 + t0;
        int row = idx >> 4, c16 = idx & 15;
        int rr = R0 + row;
        if (rr > N_NODES - 1) rr = N_NODES - 1;
        *(uint4*)&xs[row][c16 * 8] = h4[(size_t)rr * 16 + c16];
    }
    __syncthreads();
    gather_tile32(xs, rp, sinv, h4, edge_src, t0);
    const int ch = w & 1, rh = w >> 1;
    v8h wf[4][8];
#pragma unroll
    for (int t = 0; t < 4; t++)
#pragma unroll
        for (int s = 0; s < 8; s++) {
            int n = ch * 64 + t * 16 + (l & 15);
            int k = s * 32 + (l >> 4) * 8;
            wf[t][s] = *(const v8h*)&WT[n * 256 + k];
        }
    v4f acc[4];
#pragma unroll
    for (int t = 0; t < 4; t++) acc[t] = (v4f){0.f, 0.f, 0.f, 0.f};
    __syncthreads();
#pragma unroll
    for (int s = 0; s < 8; s++) {
        v8h a = *(const v8h*)&xs[rh * 16 + (l & 15)][s * 32 + (l >> 4) * 8];
#pragma unroll
        for (int t = 0; t < 4; t++)
            acc[t] = __builtin_amdgcn_mfma_f32_16x16x32_f16(a, wf[t][s], acc[t], 0, 0, 0);
    }
    __syncthreads();  // all xs reads done; safe to overwrite with h2 tile
    _Float16* hs = &xs[0][0];  // reused as [32][136]
#pragma unroll
    for (int t = 0; t < 4; t++) {
        int col = ch * 64 + t * 16 + (l & 15);
        float b = bias[col];
#pragma unroll
        for (int i = 0; i < 4; i++) {
            int lrow = rh * 16 + (l >> 4) * 4 + i;
            hs[lrow * 136 + col] = (_Float16)fmaxf(acc[t][i] + b, 0.f);
        }
    }
    __syncthreads();
    if (w < 2) {
        v8h wo[3][4];
#pragma unroll
        for (int t = 0; t < 3; t++)
#pragma unroll
            for (int s = 0; s < 4; s++) {
                int n = t * 16 + (l & 15);
                int k = s * 32 + (l >> 4) * 8;
                wo[t][s] = *(const v8h*)&WoT[n * 128 + k];
            }
        v4f acc2[3];
#pragma unroll
        for (int t = 0; t < 3; t++) acc2[t] = (v4f){0.f, 0.f, 0.f, 0.f};
#pragma unroll
        for (int s = 0; s < 4; s++) {
            v8h a = *(const v8h*)&hs[(w * 16 + (l & 15)) * 136 + s * 32 + (l >> 4) * 8];
#pragma unroll
            for (int t = 0; t < 3; t++)
                acc2[t] = __builtin_amdgcn_mfma_f32_16x16x32_f16(a, wo[t][s], acc2[t], 0, 0, 0);
        }
#pragma unroll
        for (int t = 0; t < 3; t++) {
            int col = t * 16 + (l & 15);
            if (col < 40) {
                float b = bias_o[col];
#pragma unroll
                for (int i = 0; i < 4; i++) {
                    int row = R0 + w * 16 + (l >> 4) * 4 + i;
                    if (row < N_NODES) outp[(size_t)row * 40 + col] = acc2[t][i] + b;
                }
            }
        }
    }
}

extern "C" void kernel_launch(void* const* d_in, const int* in_sizes, int n_in,
                              void* d_out, int out_size, void* d_ws, size_t ws_size,
                              hipStream_t stream) {
    int ix[8] = {0, 1, 2, 3, 4, 5, 6, 7};
    int tmp[8] = {-1, -1, -1, -1, -1, -1, -1, -1};
    for (int i = 0; i < n_in && i < 8; i++) {
        switch (in_sizes[i]) {
            case 6400000: tmp[0] = i; break;
            case 1200000: case 2400000: tmp[1] = i; break;
            case 16384:   tmp[2] = i; break;
            case 128:     tmp[3] = i; break;
            case 65536:   tmp[4] = i; break;
            case 256:     tmp[5] = i; break;
            case 5120:    tmp[6] = i; break;
            case 40:      tmp[7] = i; break;
        }
    }
    int found = 0;
    for (int j = 0; j < 8; j++) found += (tmp[j] >= 0);
    if (found == 8) for (int j = 0; j < 8; j++) ix[j] = tmp[j];

    const float* X      = (const float*)d_in[ix[0]];
    const int*   adj_w  = (const int*)d_in[ix[1]];
    const float* W_in   = (const float*)d_in[ix[2]];
    const float* b_in   = (const float*)d_in[ix[3]];
    const float* W_comb = (const float*)d_in[ix[4]];
    const float* b_comb = (const float*)d_in[ix[5]];
    const float* W_out  = (const float*)d_in[ix[6]];
    const float* b_out  = (const float*)d_in[ix[7]];
    float* out = (float*)d_out;

    // ws layout (bytes)
    char* base = (char*)d_ws;
    int*      deg      = (int*)(base + 0);           // 200000
    int*      bsync    = (int*)(base + 200000);      // 256 (zeroed with deg)
    int*      row_ptr  = (int*)(base + 200256);      // 200004
    int*      rank     = (int*)(base + 400272);      // 2400000
    float*    inv_deg  = (float*)(base + 2800272);   // 200000
    int*      edge_src = (int*)(base + 3000272);     // 2400000
    _Float16* WinT     = (_Float16*)(base + 5400272);
    _Float16* WcombT   = (_Float16*)(base + 5433040);
    _Float16* WoutT    = (_Float16*)(base + 5564112);
    _Float16* hA       = (_Float16*)(base + 5576448);
    _Float16* hB       = (_Float16*)(base + 18376448);

    hipMemsetAsync(deg, 0, 200256, stream);  // deg + bsync
    k_count_prep<<<CNT_B + WPREP_B, 256, 0, stream>>>(adj_w, deg, rank, W_in, W_comb, W_out,
                                                      WinT, WcombT, WoutT);
    k_scan<<<NBLK, 1024, 0, stream>>>(deg, row_ptr, inv_deg, bsync);
    k_fill_in<<<CNT_B + IN_B, 256, 0, stream>>>(adj_w, row_ptr, rank, edge_src,
                                                X, WinT, b_in, hA);

    k_layer<<<LYR_B, 256, 0, stream>>>(hA, WcombT, b_comb, row_ptr, edge_src, inv_deg, hB);
    k_layer_out<<<LYR_B, 256, 0, stream>>>(hB, WcombT + 32768, b_comb + 128,
                                           row_ptr, edge_src, inv_deg, WoutT, b_out, out);
}

// Round 6
// 247.989 us; speedup vs baseline: 1.1290x; 1.1029x over previous
//
#include <hip/hip_runtime.h>
#include <hip/hip_fp16.h>

#define N_NODES 50000
#define N_EDGES 600000
#define NBLK 49  // ceil(50000/1024)

typedef unsigned int u32;
typedef _Float16 v8h __attribute__((ext_vector_type(8)));
typedef _Float16 v4h __attribute__((ext_vector_type(4)));
typedef float v4f __attribute__((ext_vector_type(4)));

__device__ __forceinline__ float2 h2f2(u32 u) {
    __half2 h = *(__half2*)&u;
    return __half22float2(h);
}

// ---------------- adj layout detection (int64 vs int32), computed per-wave ----------------
__device__ __forceinline__ int calc_mode(const int* __restrict__ adj_w) {
    int l = threadIdx.x & 63;
    unsigned long long b = __ballot(adj_w[2 * l + 1] != 0);
    return (b == 0ull) ? 1 : 0;
}
// vectorized edge load: int64 mode = one uint4 (fro=lo(x), to=lo(z)); int32 = uint2
__device__ __forceinline__ void load_edge(const int* __restrict__ a, int m, int e,
                                          int& fro, int& to) {
    if (m) {
        uint4 v = ((const uint4*)a)[e];
        fro = (int)v.x;
        to = (int)v.z;
    } else {
        uint2 v = ((const uint2*)a)[e];
        fro = (int)v.x;
        to = (int)v.y;
    }
}

#define CNT_B   293    // ceil(600000/(256*8)); 8 edges per thread
#define WPREP_B 344    // ceil(88064/256)
#define IN_B    1563   // ceil(50000/32)

// ---- merged: edge count (atomic, keeps rank) + weight transpose/convert ----
__global__ void k_count_prep(const int* __restrict__ adj_w, int* __restrict__ deg,
                             int* __restrict__ rank,
                             const float* __restrict__ W_in,
                             const float* __restrict__ W_comb,
                             const float* __restrict__ W_out,
                             _Float16* __restrict__ WinT,
                             _Float16* __restrict__ WcombT,
                             _Float16* __restrict__ WoutT) {
    if (blockIdx.x < CNT_B) {
        int m = calc_mode(adj_w);
        int base = blockIdx.x * 2048 + threadIdx.x;
        int to[8], r[8];
#pragma unroll
        for (int i = 0; i < 8; i++) {
            int e = base + i * 256;
            if (e < N_EDGES) {
                int f;
                load_edge(adj_w, m, e, f, to[i]);
            } else {
                to[i] = -1;
            }
        }
#pragma unroll
        for (int i = 0; i < 8; i++)
            if (to[i] >= 0) r[i] = atomicAdd(&deg[to[i]], 1);
#pragma unroll
        for (int i = 0; i < 8; i++) {
            int e = base + i * 256;
            if (e < N_EDGES) rank[e] = r[i];
        }
        return;
    }
    int idx = (blockIdx.x - CNT_B) * 256 + threadIdx.x;
    if (idx < 16384) {
        int n = idx & 127, k = idx >> 7;
        WinT[n * 128 + k] = (_Float16)W_in[k * 128 + n];
    } else if (idx < 16384 + 65536) {
        int j = idx - 16384;
        int l = j >> 15, r = j & 32767;
        int n = r & 127, k = r >> 7;
        WcombT[l * 32768 + n * 256 + k] = (_Float16)W_comb[l * 32768 + k * 128 + n];
    } else if (idx < 16384 + 65536 + 6144) {
        int j = idx - 81920;
        int n = j >> 7, k = j & 127;
        WoutT[n * 128 + k] = (n < 40) ? (_Float16)W_out[k * 40 + n] : (_Float16)0.f;
    }
}

// ---- single-kernel CSR scan: per-block LDS scan + 49-block lookback ----
__global__ void k_scan(const int* __restrict__ deg, int* __restrict__ row_ptr,
                       float* __restrict__ inv_deg, int* __restrict__ bsync) {
    __shared__ int s[1024];
    __shared__ int sbase;
    const int tid = threadIdx.x, b = blockIdx.x;
    const int i = b * 1024 + tid;
    int v = (i < N_NODES) ? deg[i] : 0;
    s[tid] = v;
    __syncthreads();
    for (int off = 1; off < 1024; off <<= 1) {
        int t = (tid >= off) ? s[tid - off] : 0;
        __syncthreads();
        s[tid] += t;
        __syncthreads();
    }
    if (tid == 1023)
        __hip_atomic_store(&bsync[b], 0x40000000 | s[1023], __ATOMIC_RELEASE,
                           __HIP_MEMORY_SCOPE_AGENT);
    if (tid < 64) {
        int acc = 0;
        if (tid < b) {
            int x;
            do {
                x = __hip_atomic_load(&bsync[tid], __ATOMIC_ACQUIRE,
                                      __HIP_MEMORY_SCOPE_AGENT);
            } while (x < 0x40000000);
            acc = x & 0x3fffffff;
        }
#pragma unroll
        for (int off = 32; off > 0; off >>= 1) acc += __shfl_down(acc, off);
        if (tid == 0) sbase = acc;
    }
    __syncthreads();
    if (i < N_NODES) {
        row_ptr[i] = sbase + s[tid] - v;  // exclusive prefix
        inv_deg[i] = 1.0f / fmaxf((float)v, 1.0f);
    }
    if (i == 0) row_ptr[N_NODES] = N_EDGES;
}

// ---- merged: atomic-free CSR fill (rank trick) + input GEMM ----
__global__ __launch_bounds__(256, 2) void k_fill_in(const int* __restrict__ adj_w,
                                                    const int* __restrict__ row_ptr,
                                                    const int* __restrict__ rank,
                                                    int* __restrict__ edge_src,
                                                    const float* __restrict__ X,
                                                    const _Float16* __restrict__ WT,
                                                    const float* __restrict__ bias,
                                                    _Float16* __restrict__ h) {
    __shared__ __align__(16) _Float16 xs[32][136];
    if (blockIdx.x < CNT_B) {
        int m = calc_mode(adj_w);
        int base = blockIdx.x * 2048 + threadIdx.x;
        int to[8], fro[8], rk[8];
#pragma unroll
        for (int i = 0; i < 8; i++) {
            int e = base + i * 256;
            if (e < N_EDGES) {
                load_edge(adj_w, m, e, fro[i], to[i]);
                rk[i] = rank[e];
            } else {
                to[i] = -1;
            }
        }
#pragma unroll
        for (int i = 0; i < 8; i++)
            if (to[i] >= 0) edge_src[row_ptr[to[i]] + rk[i]] = fro[i];
        return;
    }
    const int t0 = threadIdx.x, w = t0 >> 6, l = t0 & 63;
    const int R0 = (blockIdx.x - CNT_B) * 32;
    const float4* X4 = (const float4*)X;
#pragma unroll
    for (int i = 0; i < 4; i++) {
        int idx = i * 256 + t0;
        int row = idx >> 5, c4 = idx & 31;
        int rr = R0 + row;
        if (rr > N_NODES - 1) rr = N_NODES - 1;
        float4 v = X4[(size_t)rr * 32 + c4];
        v4h hv = {(_Float16)v.x, (_Float16)v.y, (_Float16)v.z, (_Float16)v.w};
        *(v4h*)&xs[row][c4 * 4] = hv;
    }
    const int ch = w & 1, rh = w >> 1;
    v8h wf[4][4];
#pragma unroll
    for (int t = 0; t < 4; t++)
#pragma unroll
        for (int s = 0; s < 4; s++) {
            int n = ch * 64 + t * 16 + (l & 15);
            int k = s * 32 + (l >> 4) * 8;
            wf[t][s] = *(const v8h*)&WT[n * 128 + k];
        }
    v4f acc[4];
#pragma unroll
    for (int t = 0; t < 4; t++) acc[t] = (v4f){0.f, 0.f, 0.f, 0.f};
    __syncthreads();
#pragma unroll
    for (int s = 0; s < 4; s++) {
        v8h a = *(const v8h*)&xs[rh * 16 + (l & 15)][s * 32 + (l >> 4) * 8];
#pragma unroll
        for (int t = 0; t < 4; t++)
            acc[t] = __builtin_amdgcn_mfma_f32_16x16x32_f16(a, wf[t][s], acc[t], 0, 0, 0);
    }
#pragma unroll
    for (int t = 0; t < 4; t++) {
        int col = ch * 64 + t * 16 + (l & 15);
        float b = bias[col];
#pragma unroll
        for (int i = 0; i < 4; i++) {
            int row = R0 + rh * 16 + (l >> 4) * 4 + i;
            if (row < N_NODES)
                h[(size_t)row * 128 + col] = (_Float16)fmaxf(acc[t][i] + b, 0.f);
        }
    }
}

// ---- gather v4: dual-row per wave (2x memory-level parallelism).
// 16-lane groups x uint4 loads; 16 edges/iter/row; rows are wave-uniform so
// per-row active flags are uniform branches. ----
__global__ __launch_bounds__(256) void k_gather(const uint4* __restrict__ h16,
                                                uint4* __restrict__ msg16,
                                                const int* __restrict__ row_ptr,
                                                const int* __restrict__ edge_src,
                                                const float* __restrict__ inv_deg) {
    const int w = threadIdx.x >> 6, l = threadIdx.x & 63;
    const int grp = l >> 4, c = l & 15;  // c: which 16B chunk of the 256B row
    const int wid = blockIdx.x * 4 + w, nw = gridDim.x * 4;
    if (2 * wid >= N_NODES) return;
    // prefetch first pair's bounds
    int e00 = row_ptr[2 * wid];
    int e01 = row_ptr[2 * wid + 1];
    int e11 = row_ptr[2 * wid + 2];
    float inv0 = inv_deg[2 * wid];
    float inv1 = inv_deg[2 * wid + 1];
    for (int pr = wid; 2 * pr < N_NODES; pr += nw) {
        const int r0 = 2 * pr, r1 = r0 + 1;
        const int f00 = e00, f01 = e01, f11 = e11;
        const float i0 = inv0, i1 = inv1;
        // prefetch next pair (hidden under the gather loads)
        const int npr = pr + nw;
        if (2 * npr < N_NODES) {
            e00 = row_ptr[2 * npr];
            e01 = row_ptr[2 * npr + 1];
            e11 = row_ptr[2 * npr + 2];
            inv0 = inv_deg[2 * npr];
            inv1 = inv_deg[2 * npr + 1];
        }
        float a0[8], a1[8];
#pragma unroll
        for (int k = 0; k < 8; k++) { a0[k] = 0.f; a1[k] = 0.f; }
        int bse0 = f00, bse1 = f01;
        while (bse0 < f01 || bse1 < f11) {
            uint4 v0[4], v1[4];
            int ok0[4], ok1[4];
            const int act0 = (bse0 < f01), act1 = (bse1 < f11);  // wave-uniform
            if (act0) {
#pragma unroll
                for (int i = 0; i < 4; i++) {
                    int ee = bse0 + 4 * i + grp;
                    ok0[i] = (ee < f01);
                    int idx = ok0[i] ? ee : (f01 - 1);
                    v0[i] = h16[(size_t)edge_src[idx] * 16 + c];
                }
            }
            if (act1) {
#pragma unroll
                for (int i = 0; i < 4; i++) {
                    int ee = bse1 + 4 * i + grp;
                    ok1[i] = (ee < f11);
                    int idx = ok1[i] ? ee : (f11 - 1);
                    v1[i] = h16[(size_t)edge_src[idx] * 16 + c];
                }
            }
            if (act0) {
#pragma unroll
                for (int i = 0; i < 4; i++) {
                    if (ok0[i]) {
                        u32 u[4] = {v0[i].x, v0[i].y, v0[i].z, v0[i].w};
#pragma unroll
                        for (int k = 0; k < 4; k++) {
                            float2 f = h2f2(u[k]);
                            a0[2 * k] += f.x;
                            a0[2 * k + 1] += f.y;
                        }
                    }
                }
                bse0 += 16;
            }
            if (act1) {
#pragma unroll
                for (int i = 0; i < 4; i++) {
                    if (ok1[i]) {
                        u32 u[4] = {v1[i].x, v1[i].y, v1[i].z, v1[i].w};
#pragma unroll
                        for (int k = 0; k < 4; k++) {
                            float2 f = h2f2(u[k]);
                            a1[2 * k] += f.x;
                            a1[2 * k + 1] += f.y;
                        }
                    }
                }
                bse1 += 16;
            }
        }
#pragma unroll
        for (int k = 0; k < 8; k++) {
            a0[k] += __shfl_xor(a0[k], 16);
            a0[k] += __shfl_xor(a0[k], 32);
            a1[k] += __shfl_xor(a1[k], 16);
            a1[k] += __shfl_xor(a1[k], 32);
        }
        if (grp == 0) {
            __half2 o0 = __floats2half2_rn(a0[0] * i0, a0[1] * i0);
            __half2 o1 = __floats2half2_rn(a0[2] * i0, a0[3] * i0);
            __half2 o2 = __floats2half2_rn(a0[4] * i0, a0[5] * i0);
            __half2 o3 = __floats2half2_rn(a0[6] * i0, a0[7] * i0);
            uint4 o;
            o.x = *(u32*)&o0;
            o.y = *(u32*)&o1;
            o.z = *(u32*)&o2;
            o.w = *(u32*)&o3;
            msg16[(size_t)r0 * 16 + c] = o;
        } else if (grp == 1) {
            __half2 o0 = __floats2half2_rn(a1[0] * i1, a1[1] * i1);
            __half2 o1 = __floats2half2_rn(a1[2] * i1, a1[3] * i1);
            __half2 o2 = __floats2half2_rn(a1[4] * i1, a1[5] * i1);
            __half2 o3 = __floats2half2_rn(a1[6] * i1, a1[7] * i1);
            uint4 o;
            o.x = *(u32*)&o0;
            o.y = *(u32*)&o1;
            o.z = *(u32*)&o2;
            o.w = *(u32*)&o3;
            msg16[(size_t)r1 * 16 + c] = o;
        }
    }
}

// ---- MFMA layer GEMM: hout = relu([h|msg] @ Wc + b); M-tile 64, K=256, N=128 ----
__global__ __launch_bounds__(256, 2) void k_layer(const _Float16* __restrict__ hin,
                                                  const _Float16* __restrict__ msg,
                                                  const _Float16* __restrict__ WT,
                                                  const float* __restrict__ bias,
                                                  _Float16* __restrict__ hout) {
    __shared__ __align__(16) _Float16 xs[64][264];  // 33.8KB
    const int t0 = threadIdx.x, w = t0 >> 6, l = t0 & 63;
    const int R0 = blockIdx.x * 64;
    const uint4* h4 = (const uint4*)hin;
    const uint4* m4 = (const uint4*)msg;
#pragma unroll
    for (int i = 0; i < 8; i++) {
        int idx = i * 256 + t0;
        int row = idx >> 5, c16 = idx & 31;
        int rr = R0 + row;
        if (rr > N_NODES - 1) rr = N_NODES - 1;
        uint4 v = (c16 < 16) ? h4[(size_t)rr * 16 + c16] : m4[(size_t)rr * 16 + (c16 - 16)];
        *(uint4*)&xs[row][c16 * 8] = v;
    }
    const int ch = w & 1, rh = w >> 1;
    v8h wf[4][8];
#pragma unroll
    for (int t = 0; t < 4; t++)
#pragma unroll
        for (int s = 0; s < 8; s++) {
            int n = ch * 64 + t * 16 + (l & 15);
            int k = s * 32 + (l >> 4) * 8;
            wf[t][s] = *(const v8h*)&WT[n * 256 + k];
        }
    v4f acc[2][4];
#pragma unroll
    for (int sub = 0; sub < 2; sub++)
#pragma unroll
        for (int t = 0; t < 4; t++) acc[sub][t] = (v4f){0.f, 0.f, 0.f, 0.f};
    __syncthreads();
#pragma unroll
    for (int s = 0; s < 8; s++) {
#pragma unroll
        for (int sub = 0; sub < 2; sub++) {
            v8h a = *(const v8h*)&xs[rh * 32 + sub * 16 + (l & 15)][s * 32 + (l >> 4) * 8];
#pragma unroll
            for (int t = 0; t < 4; t++)
                acc[sub][t] = __builtin_amdgcn_mfma_f32_16x16x32_f16(a, wf[t][s], acc[sub][t], 0, 0, 0);
        }
    }
#pragma unroll
    for (int sub = 0; sub < 2; sub++)
#pragma unroll
        for (int t = 0; t < 4; t++) {
            int col = ch * 64 + t * 16 + (l & 15);
            float b = bias[col];
#pragma unroll
            for (int i = 0; i < 4; i++) {
                int row = R0 + rh * 32 + sub * 16 + (l >> 4) * 4 + i;
                if (row < N_NODES)
                    hout[(size_t)row * 128 + col] = (_Float16)fmaxf(acc[sub][t][i] + b, 0.f);
            }
        }
}

// ---- fused layer-2 + out: h2 = relu([h|msg] @ Wc + b) staged in LDS, then
// out = h2 @ W_out + b_out directly. Saves the 25.6MB hA round-trip. ----
__global__ __launch_bounds__(256, 2) void k_layer_out(const _Float16* __restrict__ hin,
                                                      const _Float16* __restrict__ msg,
                                                      const _Float16* __restrict__ WT,
                                                      const float* __restrict__ bias,
                                                      const _Float16* __restrict__ WoT,
                                                      const float* __restrict__ bias_o,
                                                      float* __restrict__ outp) {
    __shared__ __align__(16) _Float16 xs[64][264];
    const int t0 = threadIdx.x, w = t0 >> 6, l = t0 & 63;
    const int R0 = blockIdx.x * 64;
    const uint4* h4 = (const uint4*)hin;
    const uint4* m4 = (const uint4*)msg;
#pragma unroll
    for (int i = 0; i < 8; i++) {
        int idx = i * 256 + t0;
        int row = idx >> 5, c16 = idx & 31;
        int rr = R0 + row;
        if (rr > N_NODES - 1) rr = N_NODES - 1;
        uint4 v = (c16 < 16) ? h4[(size_t)rr * 16 + c16] : m4[(size_t)rr * 16 + (c16 - 16)];
        *(uint4*)&xs[row][c16 * 8] = v;
    }
    const int ch = w & 1, rh = w >> 1;
    v8h wf[4][8];
#pragma unroll
    for (int t = 0; t < 4; t++)
#pragma unroll
        for (int s = 0; s < 8; s++) {
            int n = ch * 64 + t * 16 + (l & 15);
            int k = s * 32 + (l >> 4) * 8;
            wf[t][s] = *(const v8h*)&WT[n * 256 + k];
        }
    v4f acc[2][4];
#pragma unroll
    for (int sub = 0; sub < 2; sub++)
#pragma unroll
        for (int t = 0; t < 4; t++) acc[sub][t] = (v4f){0.f, 0.f, 0.f, 0.f};
    __syncthreads();
#pragma unroll
    for (int s = 0; s < 8; s++) {
#pragma unroll
        for (int sub = 0; sub < 2; sub++) {
            v8h a = *(const v8h*)&xs[rh * 32 + sub * 16 + (l & 15)][s * 32 + (l >> 4) * 8];
#pragma unroll
            for (int t = 0; t < 4; t++)
                acc[sub][t] = __builtin_amdgcn_mfma_f32_16x16x32_f16(a, wf[t][s], acc[sub][t], 0, 0, 0);
        }
    }
    __syncthreads();  // all xs reads done; safe to overwrite with h2 tile
    _Float16* hs = &xs[0][0];  // reused as [64][136]
#pragma unroll
    for (int sub = 0; sub < 2; sub++)
#pragma unroll
        for (int t = 0; t < 4; t++) {
            int col = ch * 64 + t * 16 + (l & 15);
            float b = bias[col];
#pragma unroll
            for (int i = 0; i < 4; i++) {
                int lrow = rh * 32 + sub * 16 + (l >> 4) * 4 + i;
                hs[lrow * 136 + col] = (_Float16)fmaxf(acc[sub][t][i] + b, 0.f);
            }
        }
    v8h wo[3][4];
#pragma unroll
    for (int t = 0; t < 3; t++)
#pragma unroll
        for (int s = 0; s < 4; s++) {
            int n = t * 16 + (l & 15);
            int k = s * 32 + (l >> 4) * 8;
            wo[t][s] = *(const v8h*)&WoT[n * 128 + k];
        }
    v4f acc2[3];
#pragma unroll
    for (int t = 0; t < 3; t++) acc2[t] = (v4f){0.f, 0.f, 0.f, 0.f};
    __syncthreads();
#pragma unroll
    for (int s = 0; s < 4; s++) {
        v8h a = *(const v8h*)&hs[(w * 16 + (l & 15)) * 136 + s * 32 + (l >> 4) * 8];
#pragma unroll
        for (int t = 0; t < 3; t++)
            acc2[t] = __builtin_amdgcn_mfma_f32_16x16x32_f16(a, wo[t][s], acc2[t], 0, 0, 0);
    }
#pragma unroll
    for (int t = 0; t < 3; t++) {
        int col = t * 16 + (l & 15);
        if (col < 40) {
            float b = bias_o[col];
#pragma unroll
            for (int i = 0; i < 4; i++) {
                int row = R0 + w * 16 + (l >> 4) * 4 + i;
                if (row < N_NODES) outp[(size_t)row * 40 + col] = acc2[t][i] + b;
            }
        }
    }
}

extern "C" void kernel_launch(void* const* d_in, const int* in_sizes, int n_in,
                              void* d_out, int out_size, void* d_ws, size_t ws_size,
                              hipStream_t stream) {
    int ix[8] = {0, 1, 2, 3, 4, 5, 6, 7};
    int tmp[8] = {-1, -1, -1, -1, -1, -1, -1, -1};
    for (int i = 0; i < n_in && i < 8; i++) {
        switch (in_sizes[i]) {
            case 6400000: tmp[0] = i; break;
            case 1200000: case 2400000: tmp[1] = i; break;
            case 16384:   tmp[2] = i; break;
            case 128:     tmp[3] = i; break;
            case 65536:   tmp[4] = i; break;
            case 256:     tmp[5] = i; break;
            case 5120:    tmp[6] = i; break;
            case 40:      tmp[7] = i; break;
        }
    }
    int found = 0;
    for (int j = 0; j < 8; j++) found += (tmp[j] >= 0);
    if (found == 8) for (int j = 0; j < 8; j++) ix[j] = tmp[j];

    const float* X      = (const float*)d_in[ix[0]];
    const int*   adj_w  = (const int*)d_in[ix[1]];
    const float* W_in   = (const float*)d_in[ix[2]];
    const float* b_in   = (const float*)d_in[ix[3]];
    const float* W_comb = (const float*)d_in[ix[4]];
    const float* b_comb = (const float*)d_in[ix[5]];
    const float* W_out  = (const float*)d_in[ix[6]];
    const float* b_out  = (const float*)d_in[ix[7]];
    float* out = (float*)d_out;

    // ws layout (bytes)
    char* base = (char*)d_ws;
    int*      deg      = (int*)(base + 0);           // 200000
    int*      bsync    = (int*)(base + 200000);      // 256 (zeroed with deg)
    int*      row_ptr  = (int*)(base + 200256);      // 200004
    int*      rank     = (int*)(base + 400272);      // 2400000
    float*    inv_deg  = (float*)(base + 2800272);   // 200000
    int*      edge_src = (int*)(base + 3000272);     // 2400000
    _Float16* WinT     = (_Float16*)(base + 5400272);
    _Float16* WcombT   = (_Float16*)(base + 5433040);
    _Float16* WoutT    = (_Float16*)(base + 5564112);
    _Float16* hA       = (_Float16*)(base + 5576448);
    _Float16* hB       = (_Float16*)(base + 18376448);
    _Float16* msg      = (_Float16*)(base + 31176448);

    hipMemsetAsync(deg, 0, 200256, stream);  // deg + bsync
    k_count_prep<<<CNT_B + WPREP_B, 256, 0, stream>>>(adj_w, deg, rank, W_in, W_comb, W_out,
                                                      WinT, WcombT, WoutT);
    k_scan<<<NBLK, 1024, 0, stream>>>(deg, row_ptr, inv_deg, bsync);
    k_fill_in<<<CNT_B + IN_B, 256, 0, stream>>>(adj_w, row_ptr, rank, edge_src,
                                                X, WinT, b_in, hA);

    k_gather<<<2048, 256, 0, stream>>>((const uint4*)hA, (uint4*)msg, row_ptr, edge_src, inv_deg);
    k_layer<<<782, 256, 0, stream>>>(hA, msg, WcombT, b_comb, hB);

    k_gather<<<2048, 256, 0, stream>>>((const uint4*)hB, (uint4*)msg, row_ptr, edge_src, inv_deg);
    k_layer_out<<<782, 256, 0, stream>>>(hB, msg, WcombT + 32768, b_comb + 128,
                                         WoutT, b_out, out);
}

// Round 7
// 241.307 us; speedup vs baseline: 1.1603x; 1.0277x over previous
//
#include <hip/hip_runtime.h>
#include <hip/hip_fp16.h>

#define N_NODES 50000
#define N_EDGES 600000
#define NBLK 49  // ceil(50000/1024)

typedef unsigned int u32;
typedef _Float16 v8h __attribute__((ext_vector_type(8)));
typedef _Float16 v4h __attribute__((ext_vector_type(4)));
typedef float v4f __attribute__((ext_vector_type(4)));

__device__ __forceinline__ float2 h2f2(u32 u) {
    __half2 h = *(__half2*)&u;
    return __half22float2(h);
}

// ---------------- adj layout detection (int64 vs int32), computed per-wave ----------------
__device__ __forceinline__ int calc_mode(const int* __restrict__ adj_w) {
    int l = threadIdx.x & 63;
    unsigned long long b = __ballot(adj_w[2 * l + 1] != 0);
    return (b == 0ull) ? 1 : 0;
}
// vectorized edge load: int64 mode = one uint4 (fro=lo(x), to=lo(z)); int32 = uint2
__device__ __forceinline__ void load_edge(const int* __restrict__ a, int m, int e,
                                          int& fro, int& to) {
    if (m) {
        uint4 v = ((const uint4*)a)[e];
        fro = (int)v.x;
        to = (int)v.z;
    } else {
        uint2 v = ((const uint2*)a)[e];
        fro = (int)v.x;
        to = (int)v.y;
    }
}

#define CNT_B   293    // ceil(600000/(256*8)); 8 edges per thread
#define WPREP_B 344    // ceil(88064/256)
#define IN_B    1563   // ceil(50000/32)

// ---- merged: edge count (atomic, keeps rank) + weight transpose/convert ----
__global__ void k_count_prep(const int* __restrict__ adj_w, int* __restrict__ deg,
                             int* __restrict__ rank,
                             const float* __restrict__ W_in,
                             const float* __restrict__ W_comb,
                             const float* __restrict__ W_out,
                             _Float16* __restrict__ WinT,
                             _Float16* __restrict__ WcombT,
                             _Float16* __restrict__ WoutT) {
    if (blockIdx.x < CNT_B) {
        int m = calc_mode(adj_w);
        int base = blockIdx.x * 2048 + threadIdx.x;
        int to[8], r[8];
#pragma unroll
        for (int i = 0; i < 8; i++) {
            int e = base + i * 256;
            if (e < N_EDGES) {
                int f;
                load_edge(adj_w, m, e, f, to[i]);
            } else {
                to[i] = -1;
            }
        }
#pragma unroll
        for (int i = 0; i < 8; i++)
            if (to[i] >= 0) r[i] = atomicAdd(&deg[to[i]], 1);
#pragma unroll
        for (int i = 0; i < 8; i++) {
            int e = base + i * 256;
            if (e < N_EDGES) rank[e] = r[i];
        }
        return;
    }
    int idx = (blockIdx.x - CNT_B) * 256 + threadIdx.x;
    if (idx < 16384) {
        int n = idx & 127, k = idx >> 7;
        WinT[n * 128 + k] = (_Float16)W_in[k * 128 + n];
    } else if (idx < 16384 + 65536) {
        int j = idx - 16384;
        int l = j >> 15, r = j & 32767;
        int n = r & 127, k = r >> 7;
        WcombT[l * 32768 + n * 256 + k] = (_Float16)W_comb[l * 32768 + k * 128 + n];
    } else if (idx < 16384 + 65536 + 6144) {
        int j = idx - 81920;
        int n = j >> 7, k = j & 127;
        WoutT[n * 128 + k] = (n < 40) ? (_Float16)W_out[k * 40 + n] : (_Float16)0.f;
    }
}

// ---- single-kernel CSR scan: per-block LDS scan + 49-block lookback ----
// bsync[] must be zeroed. All 49 blocks co-resident on 256 CUs -> no deadlock.
__global__ void k_scan(const int* __restrict__ deg, int* __restrict__ row_ptr,
                       float* __restrict__ inv_deg, int* __restrict__ bsync) {
    __shared__ int s[1024];
    __shared__ int sbase;
    const int tid = threadIdx.x, b = blockIdx.x;
    const int i = b * 1024 + tid;
    int v = (i < N_NODES) ? deg[i] : 0;
    s[tid] = v;
    __syncthreads();
    for (int off = 1; off < 1024; off <<= 1) {
        int t = (tid >= off) ? s[tid - off] : 0;
        __syncthreads();
        s[tid] += t;
        __syncthreads();
    }
    if (tid == 1023)
        __hip_atomic_store(&bsync[b], 0x40000000 | s[1023], __ATOMIC_RELEASE,
                           __HIP_MEMORY_SCOPE_AGENT);
    if (tid < 64) {
        int acc = 0;
        if (tid < b) {
            int x;
            do {
                x = __hip_atomic_load(&bsync[tid], __ATOMIC_ACQUIRE,
                                      __HIP_MEMORY_SCOPE_AGENT);
            } while (x < 0x40000000);
            acc = x & 0x3fffffff;
        }
#pragma unroll
        for (int off = 32; off > 0; off >>= 1) acc += __shfl_down(acc, off);
        if (tid == 0) sbase = acc;
    }
    __syncthreads();
    if (i < N_NODES) {
        row_ptr[i] = sbase + s[tid] - v;  // exclusive prefix
        inv_deg[i] = 1.0f / fmaxf((float)v, 1.0f);
    }
    if (i == 0) row_ptr[N_NODES] = N_EDGES;
}

// ---- merged: atomic-free CSR fill (rank trick) + input GEMM ----
__global__ __launch_bounds__(256, 2) void k_fill_in(const int* __restrict__ adj_w,
                                                    const int* __restrict__ row_ptr,
                                                    const int* __restrict__ rank,
                                                    int* __restrict__ edge_src,
                                                    const float* __restrict__ X,
                                                    const _Float16* __restrict__ WT,
                                                    const float* __restrict__ bias,
                                                    _Float16* __restrict__ h) {
    __shared__ __align__(16) _Float16 xs[32][136];
    if (blockIdx.x < CNT_B) {
        int m = calc_mode(adj_w);
        int base = blockIdx.x * 2048 + threadIdx.x;
        int to[8], fro[8], rk[8];
#pragma unroll
        for (int i = 0; i < 8; i++) {
            int e = base + i * 256;
            if (e < N_EDGES) {
                load_edge(adj_w, m, e, fro[i], to[i]);
                rk[i] = rank[e];
            } else {
                to[i] = -1;
            }
        }
#pragma unroll
        for (int i = 0; i < 8; i++)
            if (to[i] >= 0) edge_src[row_ptr[to[i]] + rk[i]] = fro[i];
        return;
    }
    const int t0 = threadIdx.x, w = t0 >> 6, l = t0 & 63;
    const int R0 = (blockIdx.x - CNT_B) * 32;
    const float4* X4 = (const float4*)X;
#pragma unroll
    for (int i = 0; i < 4; i++) {
        int idx = i * 256 + t0;
        int row = idx >> 5, c4 = idx & 31;
        int rr = R0 + row;
        if (rr > N_NODES - 1) rr = N_NODES - 1;
        float4 v = X4[(size_t)rr * 32 + c4];
        v4h hv = {(_Float16)v.x, (_Float16)v.y, (_Float16)v.z, (_Float16)v.w};
        *(v4h*)&xs[row][c4 * 4] = hv;
    }
    const int ch = w & 1, rh = w >> 1;
    v8h wf[4][4];
#pragma unroll
    for (int t = 0; t < 4; t++)
#pragma unroll
        for (int s = 0; s < 4; s++) {
            int n = ch * 64 + t * 16 + (l & 15);
            int k = s * 32 + (l >> 4) * 8;
            wf[t][s] = *(const v8h*)&WT[n * 128 + k];
        }
    v4f acc[4];
#pragma unroll
    for (int t = 0; t < 4; t++) acc[t] = (v4f){0.f, 0.f, 0.f, 0.f};
    __syncthreads();
#pragma unroll
    for (int s = 0; s < 4; s++) {
        v8h a = *(const v8h*)&xs[rh * 16 + (l & 15)][s * 32 + (l >> 4) * 8];
#pragma unroll
        for (int t = 0; t < 4; t++)
            acc[t] = __builtin_amdgcn_mfma_f32_16x16x32_f16(a, wf[t][s], acc[t], 0, 0, 0);
    }
#pragma unroll
    for (int t = 0; t < 4; t++) {
        int col = ch * 64 + t * 16 + (l & 15);
        float b = bias[col];
#pragma unroll
        for (int i = 0; i < 4; i++) {
            int row = R0 + rh * 16 + (l >> 4) * 4 + i;
            if (row < N_NODES)
                h[(size_t)row * 128 + col] = (_Float16)fmaxf(acc[t][i] + b, 0.f);
        }
    }
}

// ---- gather v3: 16-lane groups x uint4 loads; 16 edges/iter; row_ptr prefetch ----
__global__ __launch_bounds__(256) void k_gather(const uint4* __restrict__ h16,
                                                uint4* __restrict__ msg16,
                                                const int* __restrict__ row_ptr,
                                                const int* __restrict__ edge_src,
                                                const float* __restrict__ inv_deg) {
    const int w = threadIdx.x >> 6, l = threadIdx.x & 63;
    const int grp = l >> 4, c = l & 15;  // c: which 16B chunk of the 256B row
    const int wid = blockIdx.x * 4 + w, nw = gridDim.x * 4;
    if (wid >= N_NODES) return;
    int pe0 = row_ptr[wid], pe1 = row_ptr[wid + 1];
    for (int row = wid; row < N_NODES; row += nw) {
        const int e0 = pe0, e1 = pe1;
        const float inv = inv_deg[row];  // issued early, hidden under gather
        const int nrow = row + nw;
        if (nrow < N_NODES) {
            pe0 = row_ptr[nrow];
            pe1 = row_ptr[nrow + 1];
        }
        float a[8];
#pragma unroll
        for (int k = 0; k < 8; k++) a[k] = 0.f;
        for (int bse = e0; bse < e1; bse += 16) {
            uint4 v[4];
            int ok[4];
#pragma unroll
            for (int i = 0; i < 4; i++) {
                int ee = bse + 4 * i + grp;
                ok[i] = (ee < e1);
                int idx = ok[i] ? ee : (e1 - 1);
                v[i] = h16[(size_t)edge_src[idx] * 16 + c];
            }
#pragma unroll
            for (int i = 0; i < 4; i++) {
                if (ok[i]) {
                    u32 u[4] = {v[i].x, v[i].y, v[i].z, v[i].w};
#pragma unroll
                    for (int k = 0; k < 4; k++) {
                        float2 f = h2f2(u[k]);
                        a[2 * k] += f.x;
                        a[2 * k + 1] += f.y;
                    }
                }
            }
        }
#pragma unroll
        for (int k = 0; k < 8; k++) {
            a[k] += __shfl_xor(a[k], 16);
            a[k] += __shfl_xor(a[k], 32);
        }
        if (grp == 0) {
            __half2 o0 = __floats2half2_rn(a[0] * inv, a[1] * inv);
            __half2 o1 = __floats2half2_rn(a[2] * inv, a[3] * inv);
            __half2 o2 = __floats2half2_rn(a[4] * inv, a[5] * inv);
            __half2 o3 = __floats2half2_rn(a[6] * inv, a[7] * inv);
            uint4 o;
            o.x = *(u32*)&o0;
            o.y = *(u32*)&o1;
            o.z = *(u32*)&o2;
            o.w = *(u32*)&o3;
            msg16[(size_t)row * 16 + c] = o;
        }
    }
}

// ---- MFMA layer GEMM: hout = relu([h|msg] @ Wc + b); M-tile 64, K=256, N=128 ----
__global__ __launch_bounds__(256, 2) void k_layer(const _Float16* __restrict__ hin,
                                                  const _Float16* __restrict__ msg,
                                                  const _Float16* __restrict__ WT,
                                                  const float* __restrict__ bias,
                                                  _Float16* __restrict__ hout) {
    __shared__ __align__(16) _Float16 xs[64][264];  // 33.8KB
    const int t0 = threadIdx.x, w = t0 >> 6, l = t0 & 63;
    const int R0 = blockIdx.x * 64;
    const uint4* h4 = (const uint4*)hin;
    const uint4* m4 = (const uint4*)msg;
#pragma unroll
    for (int i = 0; i < 8; i++) {
        int idx = i * 256 + t0;
        int row = idx >> 5, c16 = idx & 31;
        int rr = R0 + row;
        if (rr > N_NODES - 1) rr = N_NODES - 1;
        uint4 v = (c16 < 16) ? h4[(size_t)rr * 16 + c16] : m4[(size_t)rr * 16 + (c16 - 16)];
        *(uint4*)&xs[row][c16 * 8] = v;
    }
    const int ch = w & 1, rh = w >> 1;
    v8h wf[4][8];
#pragma unroll
    for (int t = 0; t < 4; t++)
#pragma unroll
        for (int s = 0; s < 8; s++) {
            int n = ch * 64 + t * 16 + (l & 15);
            int k = s * 32 + (l >> 4) * 8;
            wf[t][s] = *(const v8h*)&WT[n * 256 + k];
        }
    v4f acc[2][4];
#pragma unroll
    for (int sub = 0; sub < 2; sub++)
#pragma unroll
        for (int t = 0; t < 4; t++) acc[sub][t] = (v4f){0.f, 0.f, 0.f, 0.f};
    __syncthreads();
#pragma unroll
    for (int s = 0; s < 8; s++) {
#pragma unroll
        for (int sub = 0; sub < 2; sub++) {
            v8h a = *(const v8h*)&xs[rh * 32 + sub * 16 + (l & 15)][s * 32 + (l >> 4) * 8];
#pragma unroll
            for (int t = 0; t < 4; t++)
                acc[sub][t] = __builtin_amdgcn_mfma_f32_16x16x32_f16(a, wf[t][s], acc[sub][t], 0, 0, 0);
        }
    }
#pragma unroll
    for (int sub = 0; sub < 2; sub++)
#pragma unroll
        for (int t = 0; t < 4; t++) {
            int col = ch * 64 + t * 16 + (l & 15);
            float b = bias[col];
#pragma unroll
            for (int i = 0; i < 4; i++) {
                int row = R0 + rh * 32 + sub * 16 + (l >> 4) * 4 + i;
                if (row < N_NODES)
                    hout[(size_t)row * 128 + col] = (_Float16)fmaxf(acc[sub][t][i] + b, 0.f);
            }
        }
}

// ---- fused layer-2 + out: h2 = relu([h|msg] @ Wc + b) staged in LDS, then
// out = h2 @ W_out + b_out directly. Saves the 25.6MB hA round-trip. ----
__global__ __launch_bounds__(256, 2) void k_layer_out(const _Float16* __restrict__ hin,
                                                      const _Float16* __restrict__ msg,
                                                      const _Float16* __restrict__ WT,
                                                      const float* __restrict__ bias,
                                                      const _Float16* __restrict__ WoT,
                                                      const float* __restrict__ bias_o,
                                                      float* __restrict__ outp) {
    __shared__ __align__(16) _Float16 xs[64][264];
    const int t0 = threadIdx.x, w = t0 >> 6, l = t0 & 63;
    const int R0 = blockIdx.x * 64;
    const uint4* h4 = (const uint4*)hin;
    const uint4* m4 = (const uint4*)msg;
#pragma unroll
    for (int i = 0; i < 8; i++) {
        int idx = i * 256 + t0;
        int row = idx >> 5, c16 = idx & 31;
        int rr = R0 + row;
        if (rr > N_NODES - 1) rr = N_NODES - 1;
        uint4 v = (c16 < 16) ? h4[(size_t)rr * 16 + c16] : m4[(size_t)rr * 16 + (c16 - 16)];
        *(uint4*)&xs[row][c16 * 8] = v;
    }
    const int ch = w & 1, rh = w >> 1;
    v8h wf[4][8];
#pragma unroll
    for (int t = 0; t < 4; t++)
#pragma unroll
        for (int s = 0; s < 8; s++) {
            int n = ch * 64 + t * 16 + (l & 15);
            int k = s * 32 + (l >> 4) * 8;
            wf[t][s] = *(const v8h*)&WT[n * 256 + k];
        }
    v4f acc[2][4];
#pragma unroll
    for (int sub = 0; sub < 2; sub++)
#pragma unroll
        for (int t = 0; t < 4; t++) acc[sub][t] = (v4f){0.f, 0.f, 0.f, 0.f};
    __syncthreads();
#pragma unroll
    for (int s = 0; s < 8; s++) {
#pragma unroll
        for (int sub = 0; sub < 2; sub++) {
            v8h a = *(const v8h*)&xs[rh * 32 + sub * 16 + (l & 15)][s * 32 + (l >> 4) * 8];
#pragma unroll
            for (int t = 0; t < 4; t++)
                acc[sub][t] = __builtin_amdgcn_mfma_f32_16x16x32_f16(a, wf[t][s], acc[sub][t], 0, 0, 0);
        }
    }
    __syncthreads();  // all xs reads done; safe to overwrite with h2 tile
    _Float16* hs = &xs[0][0];  // reused as [64][136]
#pragma unroll
    for (int sub = 0; sub < 2; sub++)
#pragma unroll
        for (int t = 0; t < 4; t++) {
            int col = ch * 64 + t * 16 + (l & 15);
            float b = bias[col];
#pragma unroll
            for (int i = 0; i < 4; i++) {
                int lrow = rh * 32 + sub * 16 + (l >> 4) * 4 + i;
                hs[lrow * 136 + col] = (_Float16)fmaxf(acc[sub][t][i] + b, 0.f);
            }
        }
    v8h wo[3][4];
#pragma unroll
    for (int t = 0; t < 3; t++)
#pragma unroll
        for (int s = 0; s < 4; s++) {
            int n = t * 16 + (l & 15);
            int k = s * 32 + (l >> 4) * 8;
            wo[t][s] = *(const v8h*)&WoT[n * 128 + k];
        }
    v4f acc2[3];
#pragma unroll
    for (int t = 0; t < 3; t++) acc2[t] = (v4f){0.f, 0.f, 0.f, 0.f};
    __syncthreads();
#pragma unroll
    for (int s = 0; s < 4; s++) {
        v8h a = *(const v8h*)&hs[(w * 16 + (l & 15)) * 136 + s * 32 + (l >> 4) * 8];
#pragma unroll
        for (int t = 0; t < 3; t++)
            acc2[t] = __builtin_amdgcn_mfma_f32_16x16x32_f16(a, wo[t][s], acc2[t], 0, 0, 0);
    }
#pragma unroll
    for (int t = 0; t < 3; t++) {
        int col = t * 16 + (l & 15);
        if (col < 40) {
            float b = bias_o[col];
#pragma unroll
            for (int i = 0; i < 4; i++) {
                int row = R0 + w * 16 + (l >> 4) * 4 + i;
                if (row < N_NODES) outp[(size_t)row * 40 + col] = acc2[t][i] + b;
            }
        }
    }
}

extern "C" void kernel_launch(void* const* d_in, const int* in_sizes, int n_in,
                              void* d_out, int out_size, void* d_ws, size_t ws_size,
                              hipStream_t stream) {
    int ix[8] = {0, 1, 2, 3, 4, 5, 6, 7};
    int tmp[8] = {-1, -1, -1, -1, -1, -1, -1, -1};
    for (int i = 0; i < n_in && i < 8; i++) {
        switch (in_sizes[i]) {
            case 6400000: tmp[0] = i; break;
            case 1200000: case 2400000: tmp[1] = i; break;
            case 16384:   tmp[2] = i; break;
            case 128:     tmp[3] = i; break;
            case 65536:   tmp[4] = i; break;
            case 256:     tmp[5] = i; break;
            case 5120:    tmp[6] = i; break;
            case 40:      tmp[7] = i; break;
        }
    }
    int found = 0;
    for (int j = 0; j < 8; j++) found += (tmp[j] >= 0);
    if (found == 8) for (int j = 0; j < 8; j++) ix[j] = tmp[j];

    const float* X      = (const float*)d_in[ix[0]];
    const int*   adj_w  = (const int*)d_in[ix[1]];
    const float* W_in   = (const float*)d_in[ix[2]];
    const float* b_in   = (const float*)d_in[ix[3]];
    const float* W_comb = (const float*)d_in[ix[4]];
    const float* b_comb = (const float*)d_in[ix[5]];
    const float* W_out  = (const float*)d_in[ix[6]];
    const float* b_out  = (const float*)d_in[ix[7]];
    float* out = (float*)d_out;

    // ws layout (bytes)
    char* base = (char*)d_ws;
    int*      deg      = (int*)(base + 0);           // 200000
    int*      bsync    = (int*)(base + 200000);      // 256 (zeroed with deg)
    int*      row_ptr  = (int*)(base + 200256);      // 200004
    int*      rank     = (int*)(base + 400272);      // 2400000
    float*    inv_deg  = (float*)(base + 2800272);   // 200000
    int*      edge_src = (int*)(base + 3000272);     // 2400000
    _Float16* WinT     = (_Float16*)(base + 5400272);
    _Float16* WcombT   = (_Float16*)(base + 5433040);
    _Float16* WoutT    = (_Float16*)(base + 5564112);
    _Float16* hA       = (_Float16*)(base + 5576448);
    _Float16* hB       = (_Float16*)(base + 18376448);
    _Float16* msg      = (_Float16*)(base + 31176448);

    hipMemsetAsync(deg, 0, 200256, stream);  // deg + bsync
    k_count_prep<<<CNT_B + WPREP_B, 256, 0, stream>>>(adj_w, deg, rank, W_in, W_comb, W_out,
                                                      WinT, WcombT, WoutT);
    k_scan<<<NBLK, 1024, 0, stream>>>(deg, row_ptr, inv_deg, bsync);
    k_fill_in<<<CNT_B + IN_B, 256, 0, stream>>>(adj_w, row_ptr, rank, edge_src,
                                                X, WinT, b_in, hA);

    k_gather<<<2048, 256, 0, stream>>>((const uint4*)hA, (uint4*)msg, row_ptr, edge_src, inv_deg);
    k_layer<<<782, 256, 0, stream>>>(hA, msg, WcombT, b_comb, hB);

    k_gather<<<2048, 256, 0, stream>>>((const uint4*)hB, (uint4*)msg, row_ptr, edge_src, inv_deg);
    k_layer_out<<<782, 256, 0, stream>>>(hB, msg, WcombT + 32768, b_comb + 128,
                                         WoutT, b_out, out);
}